// Round 2
// baseline (164.195 us; speedup 1.0000x reference)
//
#include <hip/hip_runtime.h>

typedef unsigned short u16;
typedef __attribute__((ext_vector_type(8))) short short8;
typedef __attribute__((ext_vector_type(4))) float float4v;

#define D_DIM 128
#define M_DIM 128
#define BQ 4096
#define BK 8192

// round-to-nearest-even fp32 -> bf16
static __device__ inline u16 f2bf(float f) {
    unsigned int x = __float_as_uint(f);
    unsigned int r = (x + 0x7FFFu + ((x >> 16) & 1u)) >> 16;
    return (u16)r;
}

// ---------------------------------------------------------------------------
// Transpose S (128x128 row-major) into St4: St4[k4*128 + m] = S[m][4k4..4k4+3]
// so the projection hot loop can load S columns coalesced.
// ---------------------------------------------------------------------------
__global__ __launch_bounds__(256) void transpose_S(
    const float* __restrict__ S, float4v* __restrict__ St4)
{
    int t = blockIdx.x * 256 + threadIdx.x;   // 0..4095
    int m = t & 127;
    int k4 = t >> 7;
    St4[k4 * 128 + m] = *(const float4v*)&S[m * 128 + k4 * 4];
}

// ---------------------------------------------------------------------------
// Projection: X (rows x 128) @ S^T via St4 (coalesced column-slice loads).
// 16 rows/block, 256 threads: thread t -> col m = t&127, group g = t>>7
// handles 8 rows (wave-uniform LDS broadcasts for X).
// SIGNS=true : emit bf16 +-1 and normscale[row] = ||x|| * sqrt(pi/2)/128
// SIGNS=false: emit bf16 round of the projection (query path)
// ---------------------------------------------------------------------------
template <bool SIGNS>
__global__ __launch_bounds__(256) void proj_kernel(
    const float* __restrict__ X, const float4v* __restrict__ St4,
    u16* __restrict__ out, float* __restrict__ normscale)
{
    __shared__ float rows[16 * 128];  // 8 KB
    const int tid = threadIdx.x;
    const int blk = blockIdx.x;

    // stage 16 rows (2048 floats) contiguously, coalesced
    const float4v* xs = (const float4v*)(X + (size_t)blk * 16 * 128);
    float4v* ls = (float4v*)rows;
    ls[tid]       = xs[tid];
    ls[tid + 256] = xs[tid + 256];
    __syncthreads();

    const int m = tid & 127;
    const int g = tid >> 7;           // wave-uniform

    float acc[8] = {0.f, 0.f, 0.f, 0.f, 0.f, 0.f, 0.f, 0.f};

    #pragma unroll 4
    for (int k4 = 0; k4 < 32; ++k4) {
        float4v s = St4[k4 * 128 + m];          // coalesced 1KB/wave-inst
        #pragma unroll
        for (int rr = 0; rr < 8; ++rr) {
            // wave-uniform broadcast read
            float4v x = *(const float4v*)&rows[(g * 8 + rr) * 128 + k4 * 4];
            acc[rr] += s.x * x.x;
            acc[rr] += s.y * x.y;
            acc[rr] += s.z * x.z;
            acc[rr] += s.w * x.w;
        }
    }

    #pragma unroll
    for (int rr = 0; rr < 8; ++rr) {
        int row = blk * 16 + g * 8 + rr;
        u16 v;
        if (SIGNS) {
            v = (acc[rr] >= 0.f) ? (u16)0x3F80u : (u16)0xBF80u;
        } else {
            v = f2bf(acc[rr]);
        }
        out[(size_t)row * 128 + m] = v;
    }

    if (SIGNS) {
        // norms: 16 threads per row, each sums 8 squares from LDS
        const int r16 = tid >> 4;     // row 0..15
        const int seg = tid & 15;
        float p = 0.f;
        #pragma unroll
        for (int e = 0; e < 8; ++e) {
            float v = rows[r16 * 128 + seg * 8 + e];
            p += v * v;
        }
        p += __shfl_xor(p, 1);
        p += __shfl_xor(p, 2);
        p += __shfl_xor(p, 4);
        p += __shfl_xor(p, 8);
        if (seg == 0) {
            const float scale = 1.2533141373155003f / 128.0f;  // sqrt(pi/2)/m
            normscale[blk * 16 + r16] = sqrtf(p) * scale;
        }
    }
}

// ---------------------------------------------------------------------------
// Main GEMM: out[i][j] = ns[j] * sum_k qp[i][k] * sg[j][k]
// 128x128 tile per block, 4 waves in 2x2, each wave 64x64 via 4x4 frags of
// mfma_f32_16x16x32_bf16. Operands SWAPPED (mfma(b,a)) so each lane's 4
// acc regs are 4 consecutive j in one query row -> float4 coalesced stores.
// ---------------------------------------------------------------------------
__global__ __launch_bounds__(256) void qjl_gemm(
    const u16* __restrict__ qp, const u16* __restrict__ sg,
    const float* __restrict__ ns, float* __restrict__ out)
{
    __shared__ u16 Asm[128 * 136];
    __shared__ u16 Bsm[128 * 136];

    const int tid = threadIdx.x;
    const int j0 = blockIdx.x * 128;  // key tile
    const int i0 = blockIdx.y * 128;  // query tile

    const uint4* As = (const uint4*)(qp + (size_t)i0 * 128);
    const uint4* Bs = (const uint4*)(sg + (size_t)j0 * 128);
    #pragma unroll
    for (int i = 0; i < 8; ++i) {
        int c = tid + i * 256;          // 16B chunk id, 2048 per tile
        int row = c >> 4;
        int col8 = (c & 15) << 3;
        *(uint4*)&Asm[row * 136 + col8] = As[c];
        *(uint4*)&Bsm[row * 136 + col8] = Bs[c];
    }
    __syncthreads();

    const int lane = tid & 63;
    const int wid = tid >> 6;
    const int q = lane >> 4;            // quad 0..3
    const int r16 = lane & 15;
    const int wrow = (wid & 1) * 64;    // query offset of this wave
    const int wcol = (wid >> 1) * 64;   // key offset of this wave

    // acc[jt][it]: D row (q*4+rg) = key j local, D col (r16) = query i local
    float4v acc[4][4] = {};

    #pragma unroll
    for (int kk = 0; kk < 4; ++kk) {    // K steps of 32
        short8 a[4], b[4];
        #pragma unroll
        for (int t = 0; t < 4; ++t) {
            a[t] = *(const short8*)&Asm[(wrow + t * 16 + r16) * 136 + kk * 32 + q * 8];
            b[t] = *(const short8*)&Bsm[(wcol + t * 16 + r16) * 136 + kk * 32 + q * 8];
        }
        #pragma unroll
        for (int jt = 0; jt < 4; ++jt)
            #pragma unroll
            for (int it = 0; it < 4; ++it)
                acc[jt][it] = __builtin_amdgcn_mfma_f32_16x16x32_bf16(
                    b[jt], a[it], acc[jt][it], 0, 0, 0);
    }

    // epilogue: lane (q,r16): i = i0+wrow+it*16+r16, j = j0+wcol+jt*16+q*4+rg
    #pragma unroll
    for (int it = 0; it < 4; ++it) {
        const int i = i0 + wrow + it * 16 + r16;
        float* orow = out + (size_t)i * BK;
        #pragma unroll
        for (int jt = 0; jt < 4; ++jt) {
            const int jbase = j0 + wcol + jt * 16 + q * 4;
            const float4v ns4 = *(const float4v*)&ns[jbase];
            float4v v = acc[jt][it];
            v.x *= ns4.x; v.y *= ns4.y; v.z *= ns4.z; v.w *= ns4.w;
            *(float4v*)&orow[jbase] = v;
        }
    }
}

extern "C" void kernel_launch(void* const* d_in, const int* in_sizes, int n_in,
                              void* d_out, int out_size, void* d_ws, size_t ws_size,
                              hipStream_t stream) {
    const float* query    = (const float*)d_in[0];  // (4096, 128)
    const float* residual = (const float*)d_in[1];  // (8192, 128)
    const float* S        = (const float*)d_in[2];  // (128, 128)
    float* out = (float*)d_out;                     // (4096, 8192)

    char* ws = (char*)d_ws;
    u16*     qp  = (u16*)ws;                      // 1 MB
    u16*     sg  = (u16*)(ws + (1u << 20));       // 2 MB
    float*   ns  = (float*)(ws + (3u << 20));     // 32 KB
    float4v* St4 = (float4v*)(ws + (3u << 20) + (1u << 16));  // 64 KB

    transpose_S<<<dim3(16), 256, 0, stream>>>(S, St4);
    proj_kernel<false><<<dim3(BQ / 16), 256, 0, stream>>>(query, St4, qp, nullptr);
    proj_kernel<true><<<dim3(BK / 16), 256, 0, stream>>>(residual, St4, sg, ns);
    qjl_gemm<<<dim3(BK / 128, BQ / 128), 256, 0, stream>>>(qp, sg, ns, out);
}